// Round 9
// baseline (275.792 us; speedup 1.0000x reference)
//
#include <hip/hip_runtime.h>

// Problem dims
#define BB 8
#define LL 1024
#define DD 512
#define CC 4

typedef unsigned short u16;
typedef unsigned int u32;
typedef __attribute__((ext_vector_type(8))) short bf16x8;
typedef __attribute__((ext_vector_type(4))) float f32x4;
typedef __attribute__((ext_vector_type(4))) unsigned short u16x4;
typedef __attribute__((ext_vector_type(4))) float float4v;

typedef __attribute__((address_space(1))) const u32 gu32;
typedef __attribute__((address_space(3))) u32 lu32;
typedef __attribute__((address_space(3))) u16 l16;

__device__ __forceinline__ void gload16(const void* g, void* l) {
  __builtin_amdgcn_global_load_lds((gu32*)g, (lu32*)l, 16, 0, 0);
}
__device__ __forceinline__ u32 lds_off(const u16* p) {   // LDS byte offset
  return (u32)(uintptr_t)(l16*)p;
}

__device__ __forceinline__ u16 f2bf(float f) {
  unsigned u = __float_as_uint(f);
  u += 0x7FFF + ((u >> 16) & 1);   // round-to-nearest-even
  return (u16)(u >> 16);
}
__device__ __forceinline__ float bf2f(u16 h) {
  return __uint_as_float(((unsigned)h) << 16);
}
// saturation-safe fast tanh: 1 - 2/(e^{2x}+1)
__device__ __forceinline__ float fast_tanh(float x) {
  return 1.0f - 2.0f / (__expf(2.0f * x) + 1.0f);
}

// ---------------------------------------------------------------------------
// K0a: split fp32 X -> bf16 hi + bf16 lo
// ---------------------------------------------------------------------------
__global__ __launch_bounds__(256) void k_split(const float4v* __restrict__ x,
                                               u16* __restrict__ hi, u16* __restrict__ lo) {
  int i = blockIdx.x * 256 + threadIdx.x;
  float4v v = x[i];
  u16x4 h, l;
#pragma unroll
  for (int k = 0; k < 4; ++k) {
    u16 hh = f2bf(v[k]);
    h[k] = hh;
    l[k] = f2bf(v[k] - bf2f(hh));
  }
  *(u16x4*)&hi[(size_t)i * 4] = h;
  *(u16x4*)&lo[(size_t)i * 4] = l;
}

// ---------------------------------------------------------------------------
// K0b: transpose (C,D,D) weight and split to bf16 hi (+ optional lo)
// ---------------------------------------------------------------------------
__global__ __launch_bounds__(256) void k_tsplit(const float* __restrict__ w,
                                                u16* __restrict__ thi, u16* __restrict__ tlo) {
  __shared__ float t[32][33];
  int c = blockIdx.z;
  int tx = threadIdx.x;        // 0..31
  int ty = threadIdx.y;        // 0..7
  int e0 = blockIdx.x * 32, d0 = blockIdx.y * 32;
#pragma unroll
  for (int k = 0; k < 32; k += 8)
    t[ty + k][tx] = w[((size_t)c * DD + d0 + ty + k) * DD + e0 + tx];
  __syncthreads();
#pragma unroll
  for (int k = 0; k < 32; k += 8) {
    float v = t[tx][ty + k];
    size_t o = ((size_t)c * DD + e0 + ty + k) * DD + d0 + tx;
    u16 h = f2bf(v);
    thi[o] = h;
    if (tlo) tlo[o] = f2bf(v - bf2f(h));
  }
}

// ---------------------------------------------------------------------------
// Shared GEMM mainloop:  C(128x128) = A(MxK) · B(NxK)^T, both row-major stride 512.
// BK=32, TRIPLE-buffered LDS [3][128][32] u16 per operand = 48 KB total.
// 16B-slot swizzle: slot ^= (row>>1)&3, applied source-side + read-side.
// 3-deep counted-vmcnt pipeline (asm ds_read so compiler can't inject
// vmcnt(0) drains — R5 lesson / rule #18):
//   iter t: STAGE(t+2) -> vmcnt(8) -> s_barrier -> ds_read x8 -> lgkmcnt(0)
//           -> s_barrier -> setprio(1) 16 MFMA setprio(0)
// ROLLED loop (unroll 1): R8's unroll-3 bloated VGPR 72->132 and collapsed
// occupancy to ~1 block/CU; rolled body keeps ~3 waves/SIMD co-resident.
// SPLIT: 3 segments hi*hi + lo*hi + hi*lo (K-expanded 1536).
// ---------------------------------------------------------------------------
template<int NSEG, bool SPLIT>
__device__ __forceinline__ void gemm_bt(const u16* __restrict__ Ahi, const u16* __restrict__ Alo,
                                        const u16* __restrict__ Bhi, const u16* __restrict__ Blo,
                                        u16* lA, u16* lB, f32x4 (&acc)[4][4]) {
  const int tid = threadIdx.x;
  const int lane = tid & 63;
  const int wave = tid >> 6;
  const int wr = wave >> 1, wc = wave & 1;
  const int fr = lane & 15;
  const int fq = lane >> 4;                       // quarter index 0..3
  const int srow = tid >> 2;                      // 0..63
  const int xs = (tid & 3) ^ ((srow >> 1) & 3);   // pre-swizzled source slot
  const size_t soff = (size_t)srow * DD + (size_t)xs * 8;
  const int sidx = fq ^ ((fr >> 1) & 3);
  const u32 lAo = lds_off(lA), lBo = lds_off(lB);
  u32 ra[4], rb[4];
#pragma unroll
  for (int mi = 0; mi < 4; ++mi) ra[mi] = lAo + (u32)((wr * 64 + mi * 16 + fr) * 64 + sidx * 16);
#pragma unroll
  for (int ni = 0; ni < 4; ++ni) rb[ni] = lBo + (u32)((wc * 64 + ni * 16 + fr) * 64 + sidx * 16);

  const int NT = NSEG * 16;

  // beo: u16-elem offset of dest buffer (0/4096/8192); bo: byte offset (0/8192/16384)
#define STAGE(t, beo) do {                                                    \
    const int seg_ = SPLIT ? ((t) >> 4) : 0;                                  \
    const int kp_ = ((t) & 15) * 32;                                          \
    const u16* As_ = (SPLIT && seg_ == 1) ? Alo : Ahi;                        \
    const u16* Bs_ = (SPLIT && seg_ == 2) ? Blo : Bhi;                        \
    _Pragma("unroll")                                                         \
    for (int i_ = 0; i_ < 2; ++i_) {                                          \
      gload16(As_ + soff + (size_t)i_ * 64 * DD + kp_,                        \
              lA + (beo) + tid * 8 + i_ * 2048);                              \
      gload16(Bs_ + soff + (size_t)i_ * 64 * DD + kp_,                        \
              lB + (beo) + tid * 8 + i_ * 2048);                              \
    }                                                                         \
  } while (0)

#define COMPUTE(bo_) do {                                                     \
    bf16x8 af[4], bv[4];                                                      \
    _Pragma("unroll")                                                         \
    for (int mi = 0; mi < 4; ++mi)                                            \
      asm volatile("ds_read_b128 %0, %1" : "=v"(af[mi]) : "v"(ra[mi] + (bo_)));\
    _Pragma("unroll")                                                         \
    for (int ni = 0; ni < 4; ++ni)                                            \
      asm volatile("ds_read_b128 %0, %1" : "=v"(bv[ni]) : "v"(rb[ni] + (bo_)));\
    asm volatile("s_waitcnt lgkmcnt(0)" ::: "memory");                        \
    __builtin_amdgcn_sched_barrier(0);                                        \
    __builtin_amdgcn_s_barrier();  /* reads retired: buf reusable */          \
    __builtin_amdgcn_s_setprio(1);                                            \
    _Pragma("unroll")                                                         \
    for (int mi = 0; mi < 4; ++mi)                                            \
      _Pragma("unroll")                                                       \
      for (int ni = 0; ni < 4; ++ni)                                          \
        acc[mi][ni] = __builtin_amdgcn_mfma_f32_16x16x32_bf16(                \
            af[mi], bv[ni], acc[mi][ni], 0, 0, 0);                            \
    __builtin_amdgcn_s_setprio(0);                                            \
  } while (0)

  STAGE(0, 0);
  STAGE(1, 4096);
  int be = 8192;    // dest elems for stage t+2 at t=0 (buf 2)
  u32 bo = 0;       // read bytes for compute t at t=0 (buf 0)
#pragma unroll 1
  for (int t = 0; t < NT - 2; ++t) {
    STAGE(t + 2, be);
    be = (be == 8192) ? 0 : be + 4096;
    __builtin_amdgcn_sched_barrier(0);
    asm volatile("s_waitcnt vmcnt(8)" ::: "memory");   // stage(t) landed; t+1,t+2 in flight
    __builtin_amdgcn_sched_barrier(0);
    __builtin_amdgcn_s_barrier();                      // data ready
    __builtin_amdgcn_sched_barrier(0);
    COMPUTE(bo);
    bo = (bo == 16384u) ? 0u : bo + 8192u;
  }
  // peel NT-2
  __builtin_amdgcn_sched_barrier(0);
  asm volatile("s_waitcnt vmcnt(4)" ::: "memory");
  __builtin_amdgcn_sched_barrier(0);
  __builtin_amdgcn_s_barrier();
  __builtin_amdgcn_sched_barrier(0);
  COMPUTE(bo);
  bo = (bo == 16384u) ? 0u : bo + 8192u;
  // peel NT-1
  __builtin_amdgcn_sched_barrier(0);
  asm volatile("s_waitcnt vmcnt(0)" ::: "memory");
  __builtin_amdgcn_sched_barrier(0);
  __builtin_amdgcn_s_barrier();
  __builtin_amdgcn_sched_barrier(0);
  COMPUTE(bo);
#undef STAGE
#undef COMPUTE
}

// ---------------------------------------------------------------------------
// K1: mat_l[b,c] = X_b @ W_c  (split x split), epilogue splits result to bf16 hi/lo
// grid: 1024 blocks, XCD-swizzled decode (each XCD owns whole bc's)
// ---------------------------------------------------------------------------
__global__ __launch_bounds__(256) void k_matl(const u16* __restrict__ Xhi, const u16* __restrict__ Xlo,
                                              const u16* __restrict__ Whi, const u16* __restrict__ Wlo,
                                              u16* __restrict__ mhi, u16* __restrict__ mlo) {
  __shared__ u16 lA[3 * 128 * 32];
  __shared__ u16 lB[3 * 128 * 32];
  int lin = blockIdx.x;                       // 1024
  int virt = (lin & 7) * 128 + (lin >> 3);    // XCD-chunked
  int bc = virt >> 5, rem = virt & 31;
  int tm = rem >> 2, tn = rem & 3;
  int b = bc >> 2, c = bc & 3;
  const u16* Ahi = Xhi + (size_t)b * LL * DD + (size_t)tm * 128 * DD;
  const u16* Alo = Xlo + (size_t)b * LL * DD + (size_t)tm * 128 * DD;
  const u16* Bhi = Whi + (size_t)c * DD * DD + (size_t)tn * 128 * DD;
  const u16* Blo = Wlo + (size_t)c * DD * DD + (size_t)tn * 128 * DD;
  f32x4 acc[4][4];
#pragma unroll
  for (int mi = 0; mi < 4; ++mi)
#pragma unroll
    for (int ni = 0; ni < 4; ++ni) acc[mi][ni] = (f32x4){0.f, 0.f, 0.f, 0.f};
  gemm_bt<3, true>(Ahi, Alo, Bhi, Blo, lA, lB, acc);

  int lane = threadIdx.x & 63, wave = threadIdx.x >> 6;
  int wr = wave >> 1, wc = wave & 1;
  int rgrp = (lane >> 4) * 4, cidx = lane & 15;
#pragma unroll
  for (int mi = 0; mi < 4; ++mi)
#pragma unroll
    for (int ni = 0; ni < 4; ++ni) {
      int row = tm * 128 + wr * 64 + mi * 16 + rgrp;
      int col = tn * 128 + wc * 64 + ni * 16 + cidx;
#pragma unroll
      for (int j = 0; j < 4; ++j) {
        float v = acc[mi][ni][j];
        size_t o = ((size_t)bc * LL + row + j) * DD + col;
        u16 h = f2bf(v);
        mhi[o] = h;
        mlo[o] = f2bf(v - bf2f(h));
      }
    }
}

// ---------------------------------------------------------------------------
// K2: s partials: per tile of M = X_b @ mat_l[b,c]^T, tanh + row-sum
// grid: 2048 blocks, XCD-swizzled; s_part layout [bc][16][1024], slot = tn*2+wc
// ---------------------------------------------------------------------------
__global__ __launch_bounds__(256) void k_s(const u16* __restrict__ Xhi, const u16* __restrict__ Xlo,
                                           const u16* __restrict__ mhi, const u16* __restrict__ mlo,
                                           const float* __restrict__ b_l, float* __restrict__ s_part) {
  __shared__ u16 lA[3 * 128 * 32];
  __shared__ u16 lB[3 * 128 * 32];
  int lin = blockIdx.x;                       // 2048
  int virt = (lin & 7) * 256 + (lin >> 3);    // XCD-chunked
  int bc = virt >> 6, rem = virt & 63;
  int tm = rem >> 3, tn = rem & 7;
  int b = bc >> 2, c = bc & 3;
  const u16* Ahi = Xhi + (size_t)b * LL * DD + (size_t)tm * 128 * DD;
  const u16* Alo = Xlo + (size_t)b * LL * DD + (size_t)tm * 128 * DD;
  const u16* Bhi = mhi + (size_t)bc * LL * DD + (size_t)tn * 128 * DD;
  const u16* Blo = mlo + (size_t)bc * LL * DD + (size_t)tn * 128 * DD;
  f32x4 acc[4][4];
#pragma unroll
  for (int mi = 0; mi < 4; ++mi)
#pragma unroll
    for (int ni = 0; ni < 4; ++ni) acc[mi][ni] = (f32x4){0.f, 0.f, 0.f, 0.f};
  gemm_bt<3, true>(Ahi, Alo, Bhi, Blo, lA, lB, acc);

  int lane = threadIdx.x & 63, wave = threadIdx.x >> 6;
  int wr = wave >> 1, wc = wave & 1;
  float bl = b_l[c];
  float part[4][4];
#pragma unroll
  for (int mi = 0; mi < 4; ++mi)
#pragma unroll
    for (int j = 0; j < 4; ++j) part[mi][j] = 0.f;
#pragma unroll
  for (int mi = 0; mi < 4; ++mi)
#pragma unroll
    for (int ni = 0; ni < 4; ++ni)
#pragma unroll
      for (int j = 0; j < 4; ++j) part[mi][j] += fast_tanh(acc[mi][ni][j] + bl);
#pragma unroll
  for (int mi = 0; mi < 4; ++mi)
#pragma unroll
    for (int j = 0; j < 4; ++j) {
      float v = part[mi][j];
      v += __shfl_xor(v, 1, 64);
      v += __shfl_xor(v, 2, 64);
      v += __shfl_xor(v, 4, 64);
      v += __shfl_xor(v, 8, 64);
      part[mi][j] = v;
    }
  if ((lane & 15) == 0) {
    int slot = bc * 16 + tn * 2 + wc;
    int rg = (lane >> 4) * 4;
#pragma unroll
    for (int mi = 0; mi < 4; ++mi)
#pragma unroll
      for (int j = 0; j < 4; ++j) {
        int row = tm * 128 + wr * 64 + mi * 16 + rg + j;
        s_part[(size_t)slot * LL + row] = part[mi][j];
      }
  }
}

// ---------------------------------------------------------------------------
// K3: score_bar partials: sb = tanh(X_b @ w_v2[c] + b_v[c]), dot w_v1[c]
// grid: 1024 blocks, XCD-swizzled; sc_part layout [bc][8][1024], slot = tn*2+wc
// ---------------------------------------------------------------------------
__global__ __launch_bounds__(256) void k_sbar(const u16* __restrict__ Xhi, const u16* __restrict__ Wv2T,
                                              const float* __restrict__ b_v, const float* __restrict__ w_v1,
                                              float* __restrict__ sc_part) {
  __shared__ u16 lA[3 * 128 * 32];
  __shared__ u16 lB[3 * 128 * 32];
  int lin = blockIdx.x;                       // 1024
  int virt = (lin & 7) * 128 + (lin >> 3);
  int bc = virt >> 5, rem = virt & 31;
  int tm = rem >> 2, tn = rem & 3;
  int b = bc >> 2, c = bc & 3;
  const u16* Ahi = Xhi + (size_t)b * LL * DD + (size_t)tm * 128 * DD;
  const u16* Bhi = Wv2T + (size_t)c * DD * DD + (size_t)tn * 128 * DD;
  f32x4 acc[4][4];
#pragma unroll
  for (int mi = 0; mi < 4; ++mi)
#pragma unroll
    for (int ni = 0; ni < 4; ++ni) acc[mi][ni] = (f32x4){0.f, 0.f, 0.f, 0.f};
  gemm_bt<1, false>(Ahi, nullptr, Bhi, nullptr, lA, lB, acc);

  int lane = threadIdx.x & 63, wave = threadIdx.x >> 6;
  int wr = wave >> 1, wc = wave & 1;
  int cidx = lane & 15;
  float wv[4], bvv[4];
#pragma unroll
  for (int ni = 0; ni < 4; ++ni) {
    int col = tn * 128 + wc * 64 + ni * 16 + cidx;
    wv[ni] = w_v1[c * DD + col];
    bvv[ni] = b_v[c * DD + col];
  }
  float part[4][4];
#pragma unroll
  for (int mi = 0; mi < 4; ++mi)
#pragma unroll
    for (int j = 0; j < 4; ++j) part[mi][j] = 0.f;
#pragma unroll
  for (int mi = 0; mi < 4; ++mi)
#pragma unroll
    for (int ni = 0; ni < 4; ++ni)
#pragma unroll
      for (int j = 0; j < 4; ++j) part[mi][j] += fast_tanh(acc[mi][ni][j] + bvv[ni]) * wv[ni];
#pragma unroll
  for (int mi = 0; mi < 4; ++mi)
#pragma unroll
    for (int j = 0; j < 4; ++j) {
      float v = part[mi][j];
      v += __shfl_xor(v, 1, 64);
      v += __shfl_xor(v, 2, 64);
      v += __shfl_xor(v, 4, 64);
      v += __shfl_xor(v, 8, 64);
      part[mi][j] = v;
    }
  if ((lane & 15) == 0) {
    int slot = bc * 8 + tn * 2 + wc;
    int rg = (lane >> 4) * 4;
#pragma unroll
    for (int mi = 0; mi < 4; ++mi)
#pragma unroll
      for (int j = 0; j < 4; ++j) {
        int row = tm * 128 + wr * 64 + mi * 16 + rg + j;
        sc_part[(size_t)slot * LL + row] = part[mi][j];
      }
  }
}

// ---------------------------------------------------------------------------
// K4: softmaxes (a, a_bar) + pooled.  grid(32), block(1024)
// ---------------------------------------------------------------------------
__device__ __forceinline__ float blk_max(float v, float* red, int tid) {
#pragma unroll
  for (int m = 32; m >= 1; m >>= 1) v = fmaxf(v, __shfl_xor(v, m, 64));
  if ((tid & 63) == 0) red[tid >> 6] = v;
  __syncthreads();
  float r = red[0];
#pragma unroll
  for (int k = 1; k < 16; ++k) r = fmaxf(r, red[k]);
  __syncthreads();
  return r;
}
__device__ __forceinline__ float blk_sum(float v, float* red, int tid) {
#pragma unroll
  for (int m = 32; m >= 1; m >>= 1) v += __shfl_xor(v, m, 64);
  if ((tid & 63) == 0) red[tid >> 6] = v;
  __syncthreads();
  float r = red[0];
#pragma unroll
  for (int k = 1; k < 16; ++k) r += red[k];
  __syncthreads();
  return r;
}

__global__ __launch_bounds__(1024) void k_softmax(const float* __restrict__ s_part,
                                                  const float* __restrict__ sc_part,
                                                  const float* __restrict__ pad_k,
                                                  const float* __restrict__ X,
                                                  float* __restrict__ a_out,
                                                  float* __restrict__ abar_out,
                                                  float* __restrict__ pooled) {
  __shared__ float red[16];
  __shared__ float sm_abar[LL];
  __shared__ float pp[DD];
  int bc = blockIdx.x, b = bc >> 2;
  int i = threadIdx.x;
  float pk = pad_k[b * LL + i];

  float s = pk;
#pragma unroll
  for (int p = 0; p < 16; ++p) s += s_part[(size_t)(bc * 16 + p) * LL + i];
  float mx = blk_max(s, red, i);
  float e = expf(s - mx);
  float sum = blk_sum(e, red, i);
  float a = e / sum;
  a_out[bc * LL + i] = a;

  float sb = pk;
#pragma unroll
  for (int p = 0; p < 8; ++p) sb += sc_part[(size_t)(bc * 8 + p) * LL + i];
  float mx2 = blk_max(sb, red, i);
  float e2 = expf(sb - mx2);
  float sum2 = blk_sum(e2, red, i);
  float ab = e2 / sum2;
  abar_out[bc * LL + i] = ab;
  sm_abar[i] = ab;
  __syncthreads();

  // pooled GEMV over all 1024 threads: thread (h,d) sums half the L range
  {
    int d = i & (DD - 1), h = i >> 9;            // h in {0,1}
    const float* xb = X + (size_t)b * LL * DD + (size_t)h * 512 * DD + d;
    const float* abp = sm_abar + h * 512;
    float a0 = 0.f, a1 = 0.f, a2 = 0.f, a3 = 0.f;
    for (int l = 0; l < 512; l += 4) {
      a0 += abp[l + 0] * xb[(size_t)(l + 0) * DD];
      a1 += abp[l + 1] * xb[(size_t)(l + 1) * DD];
      a2 += abp[l + 2] * xb[(size_t)(l + 2) * DD];
      a3 += abp[l + 3] * xb[(size_t)(l + 3) * DD];
    }
    float sv = (a0 + a1) + (a2 + a3);
    if (h == 1) pp[d] = sv;
    __syncthreads();
    if (h == 0) pooled[bc * DD + d] = sv + pp[d];
  }
}

// ---------------------------------------------------------------------------
// K5: assemble C_features (B,L,D,5), coalesced via LDS repack.  grid(16384),256
// ---------------------------------------------------------------------------
__global__ __launch_bounds__(256) void k_assemble(const float* __restrict__ X,
                                                  const float* __restrict__ pad_k,
                                                  const float* __restrict__ a,
                                                  const float* __restrict__ pooled,
                                                  float* __restrict__ out) {
  __shared__ float buf[1280];
  int t = threadIdx.x;
  size_t idx = (size_t)blockIdx.x * 256 + t;   // flat (b,l,d)
  int d = (int)(idx & (DD - 1));
  int bl = (int)(idx >> 9);                    // b*L + l
  int b = bl >> 10;
  int l = bl & (LL - 1);
  float x = X[idx];
  float pk2 = (pad_k[bl] + 99999.0f) * (1.0f / 99999.0f);
#pragma unroll
  for (int c = 0; c < 4; ++c) {
    float av = a[(size_t)(b * 4 + c) * LL + l];
    float pv = pooled[(size_t)(b * 4 + c) * DD + d];
    buf[t * 5 + c] = av * x + pv * pk2;
  }
  buf[t * 5 + 4] = x;
  __syncthreads();
  size_t base = (size_t)blockIdx.x * 1280;
#pragma unroll
  for (int k = 0; k < 5; ++k) out[base + k * 256 + t] = buf[k * 256 + t];
}

// ---------------------------------------------------------------------------
extern "C" void kernel_launch(void* const* d_in, const int* in_sizes, int n_in,
                              void* d_out, int out_size, void* d_ws, size_t ws_size,
                              hipStream_t stream) {
  (void)in_sizes; (void)n_in; (void)out_size;
  const float* X     = (const float*)d_in[0];
  const float* pad_k = (const float*)d_in[1];
  const float* w_l   = (const float*)d_in[2];
  const float* b_l   = (const float*)d_in[3];
  const float* w_v1  = (const float*)d_in[4];
  const float* w_v2  = (const float*)d_in[5];
  const float* b_v   = (const float*)d_in[6];
  float* out = (float*)d_out;

  // Workspace layout (bytes). Xlo falls back into d_out's tail gap if ws small.
  char* wsp = (char*)d_ws;
  const size_t NEED = 26279936;
  bool small_ws = ws_size < NEED;
  u16* Xhi = (u16*)wsp;                                               // 8,388,608 B
  u16* Xlo = small_ws ? (u16*)((char*)d_out + 67108864)
                      : (u16*)(wsp + 8388608);                        // 8,388,608 B
  size_t off = small_ws ? 8388608 : 16777216;
  u16* WlThi = (u16*)(wsp + off);  off += 2097152;
  u16* WlTlo = (u16*)(wsp + off);  off += 2097152;
  u16* Wv2T  = (u16*)(wsp + off);  off += 2097152;
  float* s_part  = (float*)(wsp + off); off += 2097152;   // [32][16][1024] f32
  float* sc_part = (float*)(wsp + off); off += 1048576;   // [32][8][1024] f32
  float* pooled  = (float*)(wsp + off); off += 65536;     // [32][512] f32

  // mat_l hi/lo staged in d_out scratch (consumed before final writes).
  u16* mhi = (u16*)d_out;
  u16* mlo = (u16*)d_out + 16777216;

  float* a_out    = out + 20971520;   // (B,C,L,1)
  float* abar_out = out + 21004288;   // (B,C,L,1)

  k_split<<<4096, 256, 0, stream>>>((const float4v*)X, Xhi, Xlo);
  k_tsplit<<<dim3(16, 16, 4), dim3(32, 8), 0, stream>>>(w_l, WlThi, WlTlo);
  k_tsplit<<<dim3(16, 16, 4), dim3(32, 8), 0, stream>>>(w_v2, Wv2T, nullptr);

  k_matl<<<1024, 256, 0, stream>>>(Xhi, Xlo, WlThi, WlTlo, mhi, mlo);
  k_s<<<2048, 256, 0, stream>>>(Xhi, Xlo, mhi, mlo, b_l, s_part);
  k_sbar<<<1024, 256, 0, stream>>>(Xhi, Wv2T, b_v, w_v1, sc_part);

  k_softmax<<<32, 1024, 0, stream>>>(s_part, sc_part, pad_k, X, a_out, abar_out, pooled);
  k_assemble<<<16384, 256, 0, stream>>>(X, pad_k, a_out, pooled, out);
}

// Round 10
// 243.934 us; speedup vs baseline: 1.1306x; 1.1306x over previous
//
#include <hip/hip_runtime.h>

// Problem dims
#define BB 8
#define LL 1024
#define DD 512
#define CC 4

typedef unsigned short u16;
typedef unsigned int u32;
typedef __attribute__((ext_vector_type(8))) short bf16x8;
typedef __attribute__((ext_vector_type(4))) float f32x4;
typedef __attribute__((ext_vector_type(4))) unsigned short u16x4;
typedef __attribute__((ext_vector_type(4))) float float4v;

typedef __attribute__((address_space(1))) const u32 gu32;
typedef __attribute__((address_space(3))) u32 lu32;
typedef __attribute__((address_space(3))) u16 l16;

__device__ __forceinline__ void gload16(const void* g, void* l) {
  __builtin_amdgcn_global_load_lds((gu32*)g, (lu32*)l, 16, 0, 0);
}
__device__ __forceinline__ u32 lds_off(const u16* p) {   // LDS byte offset
  return (u32)(uintptr_t)(l16*)p;
}

__device__ __forceinline__ u16 f2bf(float f) {
  unsigned u = __float_as_uint(f);
  u += 0x7FFF + ((u >> 16) & 1);   // round-to-nearest-even
  return (u16)(u >> 16);
}
__device__ __forceinline__ float bf2f(u16 h) {
  return __uint_as_float(((unsigned)h) << 16);
}
// saturation-safe fast tanh: 1 - 2/(e^{2x}+1)
__device__ __forceinline__ float fast_tanh(float x) {
  return 1.0f - 2.0f / (__expf(2.0f * x) + 1.0f);
}

// ---------------------------------------------------------------------------
// K0a: split fp32 X -> bf16 hi + bf16 lo
// ---------------------------------------------------------------------------
__global__ __launch_bounds__(256) void k_split(const float4v* __restrict__ x,
                                               u16* __restrict__ hi, u16* __restrict__ lo) {
  int i = blockIdx.x * 256 + threadIdx.x;
  float4v v = x[i];
  u16x4 h, l;
#pragma unroll
  for (int k = 0; k < 4; ++k) {
    u16 hh = f2bf(v[k]);
    h[k] = hh;
    l[k] = f2bf(v[k] - bf2f(hh));
  }
  *(u16x4*)&hi[(size_t)i * 4] = h;
  *(u16x4*)&lo[(size_t)i * 4] = l;
}

// ---------------------------------------------------------------------------
// K0b: transpose (C,D,D) weight and split to bf16 hi (+ optional lo)
// ---------------------------------------------------------------------------
__global__ __launch_bounds__(256) void k_tsplit(const float* __restrict__ w,
                                                u16* __restrict__ thi, u16* __restrict__ tlo) {
  __shared__ float t[32][33];
  int c = blockIdx.z;
  int tx = threadIdx.x;        // 0..31
  int ty = threadIdx.y;        // 0..7
  int e0 = blockIdx.x * 32, d0 = blockIdx.y * 32;
#pragma unroll
  for (int k = 0; k < 32; k += 8)
    t[ty + k][tx] = w[((size_t)c * DD + d0 + ty + k) * DD + e0 + tx];
  __syncthreads();
#pragma unroll
  for (int k = 0; k < 32; k += 8) {
    float v = t[tx][ty + k];
    size_t o = ((size_t)c * DD + e0 + ty + k) * DD + d0 + tx;
    u16 h = f2bf(v);
    thi[o] = h;
    if (tlo) tlo[o] = f2bf(v - bf2f(h));
  }
}

// ---------------------------------------------------------------------------
// 256x256-tile GEMM mainloop: C = A(Mx K) · B(N x K)^T, row-major stride 512.
// 512 threads = 8 waves (wr=wave>>2 in 0..1, wc=wave&3 in 0..3); wave tile
// 128x64 = 8x4 frags of 16x16x32 MFMA (acc 128 VGPR).
// BK=32, TRIPLE-buffered LDS [3][256][32] u16 per operand = 96 KB total.
// 16B-slot swizzle slot^=(row>>1)&3, source-side + read-side (R7-verified,
// 0 bank conflicts).  R9-proven schedule kept verbatim:
//   iter t: STAGE(t+2) -> vmcnt(8) -> s_barrier -> asm ds_read x12 ->
//           lgkmcnt(0) -> s_barrier -> setprio(1) 32 MFMA setprio(0)
// ds_read uses one base addr + compile-time offset: immediates (VGPR diet).
// SPLIT: 3 segments hi*hi + lo*hi + hi*lo (K-expanded 1536).
// ---------------------------------------------------------------------------
#define DSR(dst, addr, OFF) \
  asm volatile("ds_read_b128 %0, %1 offset:" #OFF : "=v"(dst) : "v"(addr))

template<int NSEG, bool SPLIT>
__device__ __forceinline__ void gemm256(const u16* __restrict__ Ahi, const u16* __restrict__ Alo,
                                        const u16* __restrict__ Bhi, const u16* __restrict__ Blo,
                                        u16* lA, u16* lB, f32x4 (&acc)[8][4]) {
  const int tid = threadIdx.x;            // 0..511
  const int lane = tid & 63;
  const int wave = tid >> 6;              // 0..7
  const int wr = wave >> 2, wc = wave & 3;
  const int fr = lane & 15;
  const int fq = lane >> 4;               // quarter 0..3
  const int srow = tid >> 2;              // 0..127
  const int xs = (tid & 3) ^ ((srow >> 1) & 3);   // pre-swizzled source slot
  const size_t soff = (size_t)srow * DD + (size_t)xs * 8;
  const int sidx = fq ^ ((fr >> 1) & 3);
  const u32 ra = lds_off(lA) + (u32)((wr * 128 + fr) * 64 + sidx * 16);
  const u32 rb = lds_off(lB) + (u32)((wc * 64 + fr) * 64 + sidx * 16);

  const int NT = NSEG * 16;

  // beo: u16-elem offset of dest buffer {0,8192,16384}; bo: byte offset {0,16384,32768}
#define STAGE(t, beo) do {                                                    \
    const int seg_ = SPLIT ? ((t) >> 4) : 0;                                  \
    const int kp_ = ((t) & 15) * 32;                                          \
    const u16* As_ = (SPLIT && seg_ == 1) ? Alo : Ahi;                        \
    const u16* Bs_ = (SPLIT && seg_ == 2) ? Blo : Bhi;                        \
    _Pragma("unroll")                                                         \
    for (int i_ = 0; i_ < 2; ++i_) {                                          \
      gload16(As_ + soff + (size_t)i_ * 128 * DD + kp_,                       \
              lA + (beo) + tid * 8 + i_ * 4096);                              \
      gload16(Bs_ + soff + (size_t)i_ * 128 * DD + kp_,                       \
              lB + (beo) + tid * 8 + i_ * 4096);                              \
    }                                                                         \
  } while (0)

#define COMPUTE(bo_) do {                                                     \
    u32 aA_ = ra + (bo_), aB_ = rb + (bo_);                                   \
    bf16x8 af[8], bv[4];                                                      \
    DSR(af[0], aA_, 0);    DSR(af[1], aA_, 1024);                             \
    DSR(af[2], aA_, 2048); DSR(af[3], aA_, 3072);                             \
    DSR(af[4], aA_, 4096); DSR(af[5], aA_, 5120);                             \
    DSR(af[6], aA_, 6144); DSR(af[7], aA_, 7168);                             \
    DSR(bv[0], aB_, 0);    DSR(bv[1], aB_, 1024);                             \
    DSR(bv[2], aB_, 2048); DSR(bv[3], aB_, 3072);                             \
    asm volatile("s_waitcnt lgkmcnt(0)" ::: "memory");                        \
    __builtin_amdgcn_sched_barrier(0);                                        \
    __builtin_amdgcn_s_barrier();  /* reads retired: buf reusable */          \
    __builtin_amdgcn_s_setprio(1);                                            \
    _Pragma("unroll")                                                         \
    for (int mi = 0; mi < 8; ++mi)                                            \
      _Pragma("unroll")                                                       \
      for (int ni = 0; ni < 4; ++ni)                                          \
        acc[mi][ni] = __builtin_amdgcn_mfma_f32_16x16x32_bf16(                \
            af[mi], bv[ni], acc[mi][ni], 0, 0, 0);                            \
    __builtin_amdgcn_s_setprio(0);                                            \
  } while (0)

  STAGE(0, 0);
  STAGE(1, 8192);
  int be = 16384;   // dest elems for stage t+2 at t=0 (buf 2)
  u32 bo = 0;       // read bytes for compute t at t=0 (buf 0)
#pragma unroll 1
  for (int t = 0; t < NT - 2; ++t) {
    STAGE(t + 2, be);
    be = (be == 16384) ? 0 : be + 8192;
    __builtin_amdgcn_sched_barrier(0);
    asm volatile("s_waitcnt vmcnt(8)" ::: "memory");   // stage(t) landed; t+1,t+2 in flight
    __builtin_amdgcn_sched_barrier(0);
    __builtin_amdgcn_s_barrier();                      // data ready
    __builtin_amdgcn_sched_barrier(0);
    COMPUTE(bo);
    bo = (bo == 32768u) ? 0u : bo + 16384u;
  }
  // peel NT-2
  __builtin_amdgcn_sched_barrier(0);
  asm volatile("s_waitcnt vmcnt(4)" ::: "memory");
  __builtin_amdgcn_sched_barrier(0);
  __builtin_amdgcn_s_barrier();
  __builtin_amdgcn_sched_barrier(0);
  COMPUTE(bo);
  bo = (bo == 32768u) ? 0u : bo + 16384u;
  // peel NT-1
  __builtin_amdgcn_sched_barrier(0);
  asm volatile("s_waitcnt vmcnt(0)" ::: "memory");
  __builtin_amdgcn_sched_barrier(0);
  __builtin_amdgcn_s_barrier();
  __builtin_amdgcn_sched_barrier(0);
  COMPUTE(bo);
#undef STAGE
#undef COMPUTE
}

// ---------------------------------------------------------------------------
// K1: mat_l[b,c] = X_b @ W_c  (split x split), epilogue splits result to bf16 hi/lo
// grid: 256 blocks (tm 0..3, tn 0..1 per bc), XCD-chunked decode
// ---------------------------------------------------------------------------
__global__ __launch_bounds__(512, 2) void k_matl(const u16* __restrict__ Xhi, const u16* __restrict__ Xlo,
                                                 const u16* __restrict__ Whi, const u16* __restrict__ Wlo,
                                                 u16* __restrict__ mhi, u16* __restrict__ mlo) {
  __shared__ u16 lA[3 * 256 * 32];
  __shared__ u16 lB[3 * 256 * 32];
  int lin = blockIdx.x;                       // 256
  int virt = (lin & 7) * 32 + (lin >> 3);     // XCD-chunked
  int bc = virt >> 3, rem = virt & 7;
  int tm = rem >> 1, tn = rem & 1;
  int b = bc >> 2, c = bc & 3;
  const u16* Ahi = Xhi + (size_t)b * LL * DD + (size_t)tm * 256 * DD;
  const u16* Alo = Xlo + (size_t)b * LL * DD + (size_t)tm * 256 * DD;
  const u16* Bhi = Whi + (size_t)c * DD * DD + (size_t)tn * 256 * DD;
  const u16* Blo = Wlo + (size_t)c * DD * DD + (size_t)tn * 256 * DD;
  f32x4 acc[8][4];
#pragma unroll
  for (int mi = 0; mi < 8; ++mi)
#pragma unroll
    for (int ni = 0; ni < 4; ++ni) acc[mi][ni] = (f32x4){0.f, 0.f, 0.f, 0.f};
  gemm256<3, true>(Ahi, Alo, Bhi, Blo, lA, lB, acc);

  int lane = threadIdx.x & 63, wave = threadIdx.x >> 6;
  int wr = wave >> 2, wc = wave & 3;
  int rgrp = (lane >> 4) * 4, cidx = lane & 15;
#pragma unroll
  for (int mi = 0; mi < 8; ++mi)
#pragma unroll
    for (int ni = 0; ni < 4; ++ni) {
      int row = tm * 256 + wr * 128 + mi * 16 + rgrp;
      int col = tn * 256 + wc * 64 + ni * 16 + cidx;
#pragma unroll
      for (int j = 0; j < 4; ++j) {
        float v = acc[mi][ni][j];
        size_t o = ((size_t)bc * LL + row + j) * DD + col;
        u16 h = f2bf(v);
        mhi[o] = h;
        mlo[o] = f2bf(v - bf2f(h));
      }
    }
}

// ---------------------------------------------------------------------------
// K2: s partials: per 256x256 tile of M = X_b @ mat_l[b,c]^T, tanh + row-sum
// grid: 512 blocks, XCD-chunked; s_part [bc][16][1024], slot = tn*4+wc
// ---------------------------------------------------------------------------
__global__ __launch_bounds__(512, 2) void k_s(const u16* __restrict__ Xhi, const u16* __restrict__ Xlo,
                                              const u16* __restrict__ mhi, const u16* __restrict__ mlo,
                                              const float* __restrict__ b_l, float* __restrict__ s_part) {
  __shared__ u16 lA[3 * 256 * 32];
  __shared__ u16 lB[3 * 256 * 32];
  int lin = blockIdx.x;                       // 512
  int virt = (lin & 7) * 64 + (lin >> 3);     // XCD-chunked
  int bc = virt >> 4, rem = virt & 15;
  int tm = rem >> 2, tn = rem & 3;
  int b = bc >> 2, c = bc & 3;
  const u16* Ahi = Xhi + (size_t)b * LL * DD + (size_t)tm * 256 * DD;
  const u16* Alo = Xlo + (size_t)b * LL * DD + (size_t)tm * 256 * DD;
  const u16* Bhi = mhi + (size_t)bc * LL * DD + (size_t)tn * 256 * DD;
  const u16* Blo = mlo + (size_t)bc * LL * DD + (size_t)tn * 256 * DD;
  f32x4 acc[8][4];
#pragma unroll
  for (int mi = 0; mi < 8; ++mi)
#pragma unroll
    for (int ni = 0; ni < 4; ++ni) acc[mi][ni] = (f32x4){0.f, 0.f, 0.f, 0.f};
  gemm256<3, true>(Ahi, Alo, Bhi, Blo, lA, lB, acc);

  int lane = threadIdx.x & 63, wave = threadIdx.x >> 6;
  int wr = wave >> 2, wc = wave & 3;
  float bl = b_l[c];
  float part[8][4];
#pragma unroll
  for (int mi = 0; mi < 8; ++mi)
#pragma unroll
    for (int j = 0; j < 4; ++j) part[mi][j] = 0.f;
#pragma unroll
  for (int mi = 0; mi < 8; ++mi)
#pragma unroll
    for (int ni = 0; ni < 4; ++ni)
#pragma unroll
      for (int j = 0; j < 4; ++j) part[mi][j] += fast_tanh(acc[mi][ni][j] + bl);
#pragma unroll
  for (int mi = 0; mi < 8; ++mi)
#pragma unroll
    for (int j = 0; j < 4; ++j) {
      float v = part[mi][j];
      v += __shfl_xor(v, 1, 64);
      v += __shfl_xor(v, 2, 64);
      v += __shfl_xor(v, 4, 64);
      v += __shfl_xor(v, 8, 64);
      part[mi][j] = v;
    }
  if ((lane & 15) == 0) {
    int slot = bc * 16 + tn * 4 + wc;
    int rg = (lane >> 4) * 4;
#pragma unroll
    for (int mi = 0; mi < 8; ++mi)
#pragma unroll
      for (int j = 0; j < 4; ++j) {
        int row = tm * 256 + wr * 128 + mi * 16 + rg + j;
        s_part[(size_t)slot * LL + row] = part[mi][j];
      }
  }
}

// ---------------------------------------------------------------------------
// K3: score_bar partials: sb = tanh(X_b @ w_v2[c] + b_v[c]), dot w_v1[c]
// grid: 256 blocks, XCD-chunked; sc_part [bc][8][1024], slot = tn*4+wc
// ---------------------------------------------------------------------------
__global__ __launch_bounds__(512, 2) void k_sbar(const u16* __restrict__ Xhi, const u16* __restrict__ Wv2T,
                                                 const float* __restrict__ b_v, const float* __restrict__ w_v1,
                                                 float* __restrict__ sc_part) {
  __shared__ u16 lA[3 * 256 * 32];
  __shared__ u16 lB[3 * 256 * 32];
  int lin = blockIdx.x;                       // 256
  int virt = (lin & 7) * 32 + (lin >> 3);
  int bc = virt >> 3, rem = virt & 7;
  int tm = rem >> 1, tn = rem & 1;
  int b = bc >> 2, c = bc & 3;
  const u16* Ahi = Xhi + (size_t)b * LL * DD + (size_t)tm * 256 * DD;
  const u16* Bhi = Wv2T + (size_t)c * DD * DD + (size_t)tn * 256 * DD;
  f32x4 acc[8][4];
#pragma unroll
  for (int mi = 0; mi < 8; ++mi)
#pragma unroll
    for (int ni = 0; ni < 4; ++ni) acc[mi][ni] = (f32x4){0.f, 0.f, 0.f, 0.f};
  gemm256<1, false>(Ahi, nullptr, Bhi, nullptr, lA, lB, acc);

  int lane = threadIdx.x & 63, wave = threadIdx.x >> 6;
  int wr = wave >> 2, wc = wave & 3;
  int cidx = lane & 15;
  float wv[4], bvv[4];
#pragma unroll
  for (int ni = 0; ni < 4; ++ni) {
    int col = tn * 256 + wc * 64 + ni * 16 + cidx;
    wv[ni] = w_v1[c * DD + col];
    bvv[ni] = b_v[c * DD + col];
  }
  float part[8][4];
#pragma unroll
  for (int mi = 0; mi < 8; ++mi)
#pragma unroll
    for (int j = 0; j < 4; ++j) part[mi][j] = 0.f;
#pragma unroll
  for (int mi = 0; mi < 8; ++mi)
#pragma unroll
    for (int ni = 0; ni < 4; ++ni)
#pragma unroll
      for (int j = 0; j < 4; ++j) part[mi][j] += fast_tanh(acc[mi][ni][j] + bvv[ni]) * wv[ni];
#pragma unroll
  for (int mi = 0; mi < 8; ++mi)
#pragma unroll
    for (int j = 0; j < 4; ++j) {
      float v = part[mi][j];
      v += __shfl_xor(v, 1, 64);
      v += __shfl_xor(v, 2, 64);
      v += __shfl_xor(v, 4, 64);
      v += __shfl_xor(v, 8, 64);
      part[mi][j] = v;
    }
  if ((lane & 15) == 0) {
    int slot = bc * 8 + tn * 4 + wc;
    int rg = (lane >> 4) * 4;
#pragma unroll
    for (int mi = 0; mi < 8; ++mi)
#pragma unroll
      for (int j = 0; j < 4; ++j) {
        int row = tm * 256 + wr * 128 + mi * 16 + rg + j;
        sc_part[(size_t)slot * LL + row] = part[mi][j];
      }
  }
}

// ---------------------------------------------------------------------------
// K4: softmaxes (a, a_bar) + pooled.  grid(32), block(1024)
// ---------------------------------------------------------------------------
__device__ __forceinline__ float blk_max(float v, float* red, int tid) {
#pragma unroll
  for (int m = 32; m >= 1; m >>= 1) v = fmaxf(v, __shfl_xor(v, m, 64));
  if ((tid & 63) == 0) red[tid >> 6] = v;
  __syncthreads();
  float r = red[0];
#pragma unroll
  for (int k = 1; k < 16; ++k) r = fmaxf(r, red[k]);
  __syncthreads();
  return r;
}
__device__ __forceinline__ float blk_sum(float v, float* red, int tid) {
#pragma unroll
  for (int m = 32; m >= 1; m >>= 1) v += __shfl_xor(v, m, 64);
  if ((tid & 63) == 0) red[tid >> 6] = v;
  __syncthreads();
  float r = red[0];
#pragma unroll
  for (int k = 1; k < 16; ++k) r += red[k];
  __syncthreads();
  return r;
}

__global__ __launch_bounds__(1024) void k_softmax(const float* __restrict__ s_part,
                                                  const float* __restrict__ sc_part,
                                                  const float* __restrict__ pad_k,
                                                  const float* __restrict__ X,
                                                  float* __restrict__ a_out,
                                                  float* __restrict__ abar_out,
                                                  float* __restrict__ pooled) {
  __shared__ float red[16];
  __shared__ float sm_abar[LL];
  __shared__ float pp[DD];
  int bc = blockIdx.x, b = bc >> 2;
  int i = threadIdx.x;
  float pk = pad_k[b * LL + i];

  float s = pk;
#pragma unroll
  for (int p = 0; p < 16; ++p) s += s_part[(size_t)(bc * 16 + p) * LL + i];
  float mx = blk_max(s, red, i);
  float e = expf(s - mx);
  float sum = blk_sum(e, red, i);
  float a = e / sum;
  a_out[bc * LL + i] = a;

  float sb = pk;
#pragma unroll
  for (int p = 0; p < 8; ++p) sb += sc_part[(size_t)(bc * 8 + p) * LL + i];
  float mx2 = blk_max(sb, red, i);
  float e2 = expf(sb - mx2);
  float sum2 = blk_sum(e2, red, i);
  float ab = e2 / sum2;
  abar_out[bc * LL + i] = ab;
  sm_abar[i] = ab;
  __syncthreads();

  // pooled GEMV over all 1024 threads: thread (h,d) sums half the L range
  {
    int d = i & (DD - 1), h = i >> 9;            // h in {0,1}
    const float* xb = X + (size_t)b * LL * DD + (size_t)h * 512 * DD + d;
    const float* abp = sm_abar + h * 512;
    float a0 = 0.f, a1 = 0.f, a2 = 0.f, a3 = 0.f;
    for (int l = 0; l < 512; l += 4) {
      a0 += abp[l + 0] * xb[(size_t)(l + 0) * DD];
      a1 += abp[l + 1] * xb[(size_t)(l + 1) * DD];
      a2 += abp[l + 2] * xb[(size_t)(l + 2) * DD];
      a3 += abp[l + 3] * xb[(size_t)(l + 3) * DD];
    }
    float sv = (a0 + a1) + (a2 + a3);
    if (h == 1) pp[d] = sv;
    __syncthreads();
    if (h == 0) pooled[bc * DD + d] = sv + pp[d];
  }
}

// ---------------------------------------------------------------------------
// K5: assemble C_features (B,L,D,5), coalesced via LDS repack.  grid(16384),256
// ---------------------------------------------------------------------------
__global__ __launch_bounds__(256) void k_assemble(const float* __restrict__ X,
                                                  const float* __restrict__ pad_k,
                                                  const float* __restrict__ a,
                                                  const float* __restrict__ pooled,
                                                  float* __restrict__ out) {
  __shared__ float buf[1280];
  int t = threadIdx.x;
  size_t idx = (size_t)blockIdx.x * 256 + t;   // flat (b,l,d)
  int d = (int)(idx & (DD - 1));
  int bl = (int)(idx >> 9);                    // b*L + l
  int b = bl >> 10;
  int l = bl & (LL - 1);
  float x = X[idx];
  float pk2 = (pad_k[bl] + 99999.0f) * (1.0f / 99999.0f);
#pragma unroll
  for (int c = 0; c < 4; ++c) {
    float av = a[(size_t)(b * 4 + c) * LL + l];
    float pv = pooled[(size_t)(b * 4 + c) * DD + d];
    buf[t * 5 + c] = av * x + pv * pk2;
  }
  buf[t * 5 + 4] = x;
  __syncthreads();
  size_t base = (size_t)blockIdx.x * 1280;
#pragma unroll
  for (int k = 0; k < 5; ++k) out[base + k * 256 + t] = buf[k * 256 + t];
}

// ---------------------------------------------------------------------------
extern "C" void kernel_launch(void* const* d_in, const int* in_sizes, int n_in,
                              void* d_out, int out_size, void* d_ws, size_t ws_size,
                              hipStream_t stream) {
  (void)in_sizes; (void)n_in; (void)out_size;
  const float* X     = (const float*)d_in[0];
  const float* pad_k = (const float*)d_in[1];
  const float* w_l   = (const float*)d_in[2];
  const float* b_l   = (const float*)d_in[3];
  const float* w_v1  = (const float*)d_in[4];
  const float* w_v2  = (const float*)d_in[5];
  const float* b_v   = (const float*)d_in[6];
  float* out = (float*)d_out;

  // Workspace layout (bytes). Xlo falls back into d_out's tail gap if ws small.
  char* wsp = (char*)d_ws;
  const size_t NEED = 26279936;
  bool small_ws = ws_size < NEED;
  u16* Xhi = (u16*)wsp;                                               // 8,388,608 B
  u16* Xlo = small_ws ? (u16*)((char*)d_out + 67108864)
                      : (u16*)(wsp + 8388608);                        // 8,388,608 B
  size_t off = small_ws ? 8388608 : 16777216;
  u16* WlThi = (u16*)(wsp + off);  off += 2097152;
  u16* WlTlo = (u16*)(wsp + off);  off += 2097152;
  u16* Wv2T  = (u16*)(wsp + off);  off += 2097152;
  float* s_part  = (float*)(wsp + off); off += 2097152;   // [32][16][1024] f32
  float* sc_part = (float*)(wsp + off); off += 1048576;   // [32][8][1024] f32
  float* pooled  = (float*)(wsp + off); off += 65536;     // [32][512] f32

  // mat_l hi/lo staged in d_out scratch (consumed before final writes).
  u16* mhi = (u16*)d_out;
  u16* mlo = (u16*)d_out + 16777216;

  float* a_out    = out + 20971520;   // (B,C,L,1)
  float* abar_out = out + 21004288;   // (B,C,L,1)

  k_split<<<4096, 256, 0, stream>>>((const float4v*)X, Xhi, Xlo);
  k_tsplit<<<dim3(16, 16, 4), dim3(32, 8), 0, stream>>>(w_l, WlThi, WlTlo);
  k_tsplit<<<dim3(16, 16, 4), dim3(32, 8), 0, stream>>>(w_v2, Wv2T, nullptr);

  k_matl<<<256, 512, 0, stream>>>(Xhi, Xlo, WlThi, WlTlo, mhi, mlo);
  k_s<<<512, 512, 0, stream>>>(Xhi, Xlo, mhi, mlo, b_l, s_part);
  k_sbar<<<256, 512, 0, stream>>>(Xhi, Wv2T, b_v, w_v1, sc_part);

  k_softmax<<<32, 1024, 0, stream>>>(s_part, sc_part, pad_k, X, a_out, abar_out, pooled);
  k_assemble<<<16384, 256, 0, stream>>>(X, pad_k, a_out, pooled, out);
}